// Round 4
// baseline (845.191 us; speedup 1.0000x reference)
//
#include <hip/hip_runtime.h>

// Corr1d_x: out[n,ch,h,w] = (1/C) * sum_c img1[n,c,h,w] * img2[n,c,h,w + (ch-23)]
// Shapes: img1,img2 [8,256,128,256] fp32; out [8,27,128,256] fp32.
// v4: v3 with the stage() channel-index bug fixed (stage((k+1)*CHUNK,...)).
//     Barrier-free main loop. 1024 blocks x 4 waves; each wave owns one
//     (n,h) row and a 64-channel C-quarter, staging img2 rows into its OWN
//     LDS double-buffer (no cross-wave sync; per-wave s_waitcnt vmcnt(0)).
//     36.9KB LDS/block -> 4 blocks/CU = 16 independent waves/CU.

#define N_      8
#define C_      256
#define H_      128
#define W_      256
#define NCH     27
#define NCQ     64                   // channels per wave
#define CHUNK   4                    // c-slices per pipeline step
#define NCHUNK  (NCQ / CHUNK)        // 16
#define LROW    288                  // 24 left pad + 256 + 8 right pad
#define PADL    24
#define WLDS    (2 * CHUNK * LROW)   // floats per wave region (dbuf) = 2304
#define SMEM_FLOATS (4 * WLDS)       // 36864 B

__device__ __forceinline__ void async_cp16(const float* g, float* l) {
  __builtin_amdgcn_global_load_lds(
      (const __attribute__((address_space(1))) void*)g,
      (__attribute__((address_space(3))) void*)l,
      16, 0, 0);
}

__global__ __launch_bounds__(256, 4)
void corr1d_kernel(const float* __restrict__ img1,
                   const float* __restrict__ img2,
                   float* __restrict__ out) {
  __shared__ __align__(16) float smem[SMEM_FLOATS];

  const int tid  = threadIdx.x;
  const int wv   = tid >> 6;          // 0..3 -> C-quarter
  const int lane = tid & 63;
  const int w0   = lane << 2;         // lane owns outputs w0..w0+3

  const int nh = blockIdx.x;          // one (n,h) row per block
  const int n  = nh >> 7;
  const int h  = nh & (H_ - 1);

  float* wbase = &smem[wv * WLDS];

  // Zero ONLY the pad columns of this wave's region (payload is written
  // solely by the LDS-DMA, so no zero-vs-DMA ordering hazard).
  {
    // 8 rows x 32 pad floats = 256 floats; 4 per lane (float4, both pad
    // blocks are 16B-aligned: offsets 0..20 and 280..284 -> x4 bytes).
    const int row = lane >> 3;             // (lane*4)/32
    const int j   = (lane & 7) << 2;       // 0,4,..,28
    const int off = (j < PADL) ? j : j + 256;   // [0,24) or [280,288)
    *(float4*)(wbase + row * LROW + off) = make_float4(0.f, 0.f, 0.f, 0.f);
  }

  const size_t plane = (size_t)H_ * W_;
  const float* i1p = img1 + ((size_t)n * C_ + wv * NCQ) * plane
                          + (size_t)h * W_ + w0;
  const float* i2p = img2 + ((size_t)n * C_ + wv * NCQ) * plane
                          + (size_t)h * W_ + w0;   // lane*16B for gload_lds

  auto stage = [&](int c0, int buf) {
    #pragma unroll
    for (int r = 0; r < CHUNK; ++r)
      async_cp16(i2p + (size_t)(c0 + r) * plane,
                 wbase + (buf * CHUNK + r) * LROW + PADL);
  };

  float4 p[CHUNK];
  float4 acc[NCH];
  #pragma unroll
  for (int ch = 0; ch < NCH; ++ch) acc[ch] = make_float4(0.f, 0.f, 0.f, 0.f);

  stage(0, 0);
  #pragma unroll
  for (int r = 0; r < CHUNK; ++r)
    p[r] = *(const float4*)(i1p + (size_t)r * plane);

  for (int k = 0; k < NCHUNK; ++k) {
    // Per-wave wait: chunk k's DMA + img1 loads are the only outstanding
    // vmem ops. No __syncthreads -- waves run free.
    asm volatile("s_waitcnt vmcnt(0)" ::: "memory");
    const int buf = k & 1;
    const bool more = (k + 1 < NCHUNK);
    const int c0n = (k + 1) * CHUNK;
    if (more) stage(c0n, buf ^ 1);

    #pragma unroll
    for (int r = 0; r < CHUNK; ++r) {
      const float4 a = p[r];
      if (more)
        p[r] = *(const float4*)(i1p + (size_t)(c0n + r) * plane);
      const float4* lrow =
          (const float4*)(wbase + (buf * CHUNK + r) * LROW + w0);
      float f[32];
      #pragma unroll
      for (int q = 0; q < 8; ++q) {
        float4 t = lrow[q];
        f[4*q] = t.x; f[4*q+1] = t.y; f[4*q+2] = t.z; f[4*q+3] = t.w;
      }
      #pragma unroll
      for (int ch = 0; ch < NCH; ++ch) {
        // img2[w0+j+ch-23] -> padded slot w0 + j + ch + 1 -> f[j+ch+1]
        acc[ch].x = fmaf(a.x, f[ch + 1], acc[ch].x);
        acc[ch].y = fmaf(a.y, f[ch + 2], acc[ch].y);
        acc[ch].z = fmaf(a.z, f[ch + 3], acc[ch].z);
        acc[ch].w = fmaf(a.w, f[ch + 4], acc[ch].w);
      }
    }
  }

  // Combine the four C-quarters. Reduction region (27*64 float4 = 27.6KB)
  // reuses the staging LDS; 3 serial rounds, conflict-free [ch][lane] layout.
  float4* red = (float4*)smem;
  __syncthreads();                    // all staging reads done
  #pragma unroll 1
  for (int s = 1; s < 4; ++s) {
    if (wv == s) {
      #pragma unroll
      for (int ch = 0; ch < NCH; ++ch) red[ch * 64 + lane] = acc[ch];
    }
    __syncthreads();
    if (wv == 0) {
      #pragma unroll
      for (int ch = 0; ch < NCH; ++ch) {
        float4 t = red[ch * 64 + lane];
        acc[ch].x += t.x; acc[ch].y += t.y; acc[ch].z += t.z; acc[ch].w += t.w;
      }
    }
    __syncthreads();
  }

  if (wv == 0) {
    const float scale = 1.0f / C_;
    float* op = out + (size_t)n * NCH * plane + (size_t)h * W_ + w0;
    #pragma unroll
    for (int ch = 0; ch < NCH; ++ch) {
      float4 v = make_float4(acc[ch].x * scale, acc[ch].y * scale,
                             acc[ch].z * scale, acc[ch].w * scale);
      *(float4*)(op + (size_t)ch * plane) = v;
    }
  }
}

extern "C" void kernel_launch(void* const* d_in, const int* in_sizes, int n_in,
                              void* d_out, int out_size, void* d_ws, size_t ws_size,
                              hipStream_t stream) {
  const float* img1 = (const float*)d_in[0];
  const float* img2 = (const float*)d_in[1];
  float* out = (float*)d_out;
  corr1d_kernel<<<dim3(N_ * H_), dim3(256), 0, stream>>>(img1, img2, out);
}